// Round 14
// baseline (54.978 us; speedup 1.0000x reference)
//
#include <hip/hip_runtime.h>

#define IMG 256
#define CROPW 230
#define REMAIN 115
#define NGROUP 16          // channel groups per batch
#define GCH    32          // channels per group (16*32 = 512)

typedef float f32x4_t __attribute__((ext_vector_type(4)));

__device__ __forceinline__ int cut_start(int v) {
    int xy = IMG - v;
    return (v <= REMAIN) ? 0 : ((xy <= REMAIN) ? (IMG - CROPW) : (v - REMAIN));
}

// Grid: 128*16 blocks. Each block: 32 channels of one batch -> partial cam[256].
__global__ __launch_bounds__(256) void cam_partial_kernel(
    const float* __restrict__ fm, float* __restrict__ cam_part)
{
    const int blk = blockIdx.x;
    const int b = blk >> 4;
    const int g = blk & (NGROUP - 1);
    const int tid = threadIdx.x;
    const int lane = tid & 63;
    const int wave = tid >> 6;

    __shared__ float tile[GCH * 256];   // 32 KB
    __shared__ float fw[GCH];

    const float* src = fm + ((size_t)b * 512 + (size_t)g * GCH) * 256;

    const float4* src4 = (const float4*)src;
    float4* tile4 = (float4*)tile;
    #pragma unroll
    for (int k = 0; k < 8; ++k)
        tile4[tid + k * 256] = src4[tid + k * 256];
    __syncthreads();

    for (int c = wave * 8; c < wave * 8 + 8; ++c) {
        const float* row = tile + c * 256;
        float s = row[lane] + row[lane + 64] + row[lane + 128] + row[lane + 192];
        #pragma unroll
        for (int off = 32; off >= 1; off >>= 1)
            s += __shfl_xor(s, off, 64);
        if (lane == 0) fw[c] = s * (1.0f / 256.0f);
    }
    __syncthreads();

    float acc = 0.0f;
    #pragma unroll
    for (int c = 0; c < GCH; ++c) {
        float v = fw[c] * tile[c * 256 + tid];
        acc += (v > 0.0f) ? v : 0.0f;
    }
    cam_part[(size_t)blk * 256 + tid] = acc;   // positive 1/512 scale dropped (argmax-invariant)
}

// Grid: 128 blocks. Sum the 16 partials, argmax (first-occurrence), crop origin.
__global__ __launch_bounds__(256) void argmax_kernel(
    const float* __restrict__ cam_part, int* __restrict__ se_out)
{
    const int b = blockIdx.x;
    const int tid = threadIdx.x;

    __shared__ float s_val[256];
    __shared__ int   s_idx[256];

    float acc = 0.0f;
    #pragma unroll
    for (int g = 0; g < NGROUP; ++g)
        acc += cam_part[((size_t)b * NGROUP + g) * 256 + tid];

    s_val[tid] = acc;
    s_idx[tid] = tid;
    __syncthreads();

    for (int stride = 128; stride >= 1; stride >>= 1) {
        if (tid < stride) {
            float v2 = s_val[tid + stride]; int i2 = s_idx[tid + stride];
            float v1 = s_val[tid];          int i1 = s_idx[tid];
            if (v2 > v1 || (v2 == v1 && i2 < i1)) { s_val[tid] = v2; s_idx[tid] = i2; }
        }
        __syncthreads();
    }

    if (tid == 0) {
        int idx = s_idx[0];
        int fx = idx >> 4, fy = idx & 15;      // H = W = 16
        int ix = 16 * fx,  iy = 16 * fy;       // IMG*fx//H
        se_out[2 * b]     = cut_start(ix);
        se_out[2 * b + 1] = cut_start(iy);
    }
}

// K2: bilinear, direct from global, BLOCK = ONE WHOLE IMAGE (grid 384 x 1024).
// Thread = 4 adjacent cols x 16 rows (row stride 16). ~1.5 blocks/CU keeps the
// instantaneous per-CU read window ~32 KB -> the 2.2x column-window read
// amplification is served by L1 instead of thrashing L1/L2 (round-13 theory).
// No LDS, no barriers. Per-pixel fp32 math identical to rounds 11-13 (verified).
__global__ __launch_bounds__(1024) void bilinear_img_kernel(
    const float* __restrict__ x, const int* __restrict__ se, float* __restrict__ out)
{
    const int bc = blockIdx.x;              // image index (b*3 + c), 0..383
    const int b  = bc / 3;
    const int tid = threadIdx.x;

    const int x0 = se[2 * b];
    const int y0 = se[2 * b + 1];

    const float scale = (float)(229.0 / 255.0);   // (CROP-1)/(IMG-1) in fp32

    // Thread = output columns [4*jq, 4*jq+4), rows il = rr + 16*k.
    const int jq = tid & 63;
    const int rr = tid >> 6;                // 0..15
    const int jb0 = 4 * jq;

    const float sj0 = (float)(jb0    ) * scale; const int a0 = (int)floorf(sj0); const float wj0 = sj0 - (float)a0;
    const float sj1 = (float)(jb0 + 1) * scale; const int a1 = (int)floorf(sj1); const float wj1 = sj1 - (float)a1;
    const float sj2 = (float)(jb0 + 2) * scale; const int a2 = (int)floorf(sj2); const float wj2 = sj2 - (float)a2;
    const float sj3 = (float)(jb0 + 3) * scale; const int a3 = (int)floorf(sj3); const float wj3 = sj3 - (float)a3;

    // Relative source-column indices (proven ranges): d1∈{0,1} d2∈{1,2} d3∈{2,3};
    // e3∈{2,3,4} (col 255 can clamp at 229).
    const int  d1 = a1 - a0;
    const int  d2 = a2 - a0;
    const int  d3 = a3 - a0;
    const int  e3 = min(a3 + 1, CROPW - 1) - a0;
    const int  cA = y0 + a0;
    const int  c4 = min(cA + 4, 255);       // clamp only when rb4 unused

    const float owj0 = 1.0f - wj0, owj1 = 1.0f - wj1;
    const float owj2 = 1.0f - wj2, owj3 = 1.0f - wj3;

    const float* img = x + (size_t)bc * (IMG * IMG);
    float* outbase = out + (size_t)bc * (IMG * IMG) + jb0;

    #pragma unroll
    for (int k = 0; k < 16; ++k) {
        const int   i  = rr + 16 * k;       // output row
        const float si = (float)i * scale;
        const int   i0 = (int)floorf(si);
        const float wi = si - (float)i0;
        const int   i1 = min(i0 + 1, CROPW - 1);
        const int   r0g = (x0 + i0) << 8;
        const int   r1g = (x0 + i1) << 8;
        const float owi = 1.0f - wi;

        // Unaligned (4B-aligned) vector loads: HW dwordx4 needs only dword align.
        f32x4_t v, u;
        __builtin_memcpy(&v, img + r0g + cA, sizeof(f32x4_t));
        __builtin_memcpy(&u, img + r1g + cA, sizeof(f32x4_t));
        const float v4s = img[r0g + c4];
        const float u4s = img[r1g + c4];

        // Vertical blend once per source column (== reference "rows" values).
        const float rb0 = v.x * owi + u.x * wi;
        const float rb1 = v.y * owi + u.y * wi;
        const float rb2 = v.z * owi + u.z * wi;
        const float rb3 = v.w * owi + u.w * wi;
        const float rb4 = v4s * owi + u4s * wi;

        // Horizontal blend per pixel (static-range selects).
        const float o0 = rb0 * owj0 + rb1 * wj0;

        const float A1 = d1 ? rb1 : rb0;
        const float B1 = d1 ? rb2 : rb1;
        const float o1 = A1 * owj1 + B1 * wj1;

        const float A2 = (d2 == 2) ? rb2 : rb1;
        const float B2 = (d2 == 2) ? rb3 : rb2;
        const float o2 = A2 * owj2 + B2 * wj2;

        const float A3 = (d3 == 3) ? rb3 : rb2;
        const float B3 = (e3 == 2) ? rb2 : ((e3 == 3) ? rb3 : rb4);
        const float o3 = A3 * owj3 + B3 * wj3;

        f32x4_t o; o.x = o0; o.y = o1; o.z = o2; o.w = o3;
        __builtin_nontemporal_store(o, (f32x4_t*)(outbase + (size_t)i * IMG));
    }
}

extern "C" void kernel_launch(void* const* d_in, const int* in_sizes, int n_in,
                              void* d_out, int out_size, void* d_ws, size_t ws_size,
                              hipStream_t stream) {
    const float* x  = (const float*)d_in[0];   // (128,3,256,256)
    const float* fm = (const float*)d_in[1];   // (128,512,16,16)
    float* out = (float*)d_out;                // (128,3,256,256)

    int*   se       = (int*)d_ws;                               // 128*2 ints
    float* cam_part = (float*)((char*)d_ws + 1024);             // 2 MB

    cam_partial_kernel<<<128 * NGROUP, 256, 0, stream>>>(fm, cam_part);
    argmax_kernel<<<128, 256, 0, stream>>>(cam_part, se);

    bilinear_img_kernel<<<384, 1024, 0, stream>>>(x, se, out);
}

// Round 15
// 50.029 us; speedup vs baseline: 1.0989x; 1.0989x over previous
//
#include <hip/hip_runtime.h>

#define IMG 256
#define CROPW 230
#define REMAIN 115
#define NGROUP 16          // channel groups per batch
#define GCH    32          // channels per group (16*32 = 512)
#define TILE_I 16          // output rows per bilinear block-band
#define NTILE  16          // bands per image (256 / TILE_I)

typedef float f32x4_t __attribute__((ext_vector_type(4)));

__device__ __forceinline__ int cut_start(int v) {
    int xy = IMG - v;
    return (v <= REMAIN) ? 0 : ((xy <= REMAIN) ? (IMG - CROPW) : (v - REMAIN));
}

// Grid: 128*16 blocks. Each block: 32 channels of one batch -> partial cam[256].
__global__ __launch_bounds__(256) void cam_partial_kernel(
    const float* __restrict__ fm, float* __restrict__ cam_part)
{
    const int blk = blockIdx.x;
    const int b = blk >> 4;
    const int g = blk & (NGROUP - 1);
    const int tid = threadIdx.x;
    const int lane = tid & 63;
    const int wave = tid >> 6;

    __shared__ float tile[GCH * 256];   // 32 KB
    __shared__ float fw[GCH];

    const float* src = fm + ((size_t)b * 512 + (size_t)g * GCH) * 256;

    const float4* src4 = (const float4*)src;
    float4* tile4 = (float4*)tile;
    #pragma unroll
    for (int k = 0; k < 8; ++k)
        tile4[tid + k * 256] = src4[tid + k * 256];
    __syncthreads();

    for (int c = wave * 8; c < wave * 8 + 8; ++c) {
        const float* row = tile + c * 256;
        float s = row[lane] + row[lane + 64] + row[lane + 128] + row[lane + 192];
        #pragma unroll
        for (int off = 32; off >= 1; off >>= 1)
            s += __shfl_xor(s, off, 64);
        if (lane == 0) fw[c] = s * (1.0f / 256.0f);
    }
    __syncthreads();

    float acc = 0.0f;
    #pragma unroll
    for (int c = 0; c < GCH; ++c) {
        float v = fw[c] * tile[c * 256 + tid];
        acc += (v > 0.0f) ? v : 0.0f;
    }
    cam_part[(size_t)blk * 256 + tid] = acc;   // positive 1/512 scale dropped (argmax-invariant)
}

// Grid: 128 blocks. Sum the 16 partials, argmax (first-occurrence), crop origin.
__global__ __launch_bounds__(256) void argmax_kernel(
    const float* __restrict__ cam_part, int* __restrict__ se_out)
{
    const int b = blockIdx.x;
    const int tid = threadIdx.x;

    __shared__ float s_val[256];
    __shared__ int   s_idx[256];

    float acc = 0.0f;
    #pragma unroll
    for (int g = 0; g < NGROUP; ++g)
        acc += cam_part[((size_t)b * NGROUP + g) * 256 + tid];

    s_val[tid] = acc;
    s_idx[tid] = tid;
    __syncthreads();

    for (int stride = 128; stride >= 1; stride >>= 1) {
        if (tid < stride) {
            float v2 = s_val[tid + stride]; int i2 = s_idx[tid + stride];
            float v1 = s_val[tid];          int i1 = s_idx[tid];
            if (v2 > v1 || (v2 == v1 && i2 < i1)) { s_val[tid] = v2; s_idx[tid] = i2; }
        }
        __syncthreads();
    }

    if (tid == 0) {
        int idx = s_idx[0];
        int fx = idx >> 4, fy = idx & 15;      // H = W = 16
        int ix = 16 * fx,  iy = 16 * fy;       // IMG*fx//H
        se_out[2 * b]     = cut_start(ix);
        se_out[2 * b + 1] = cut_start(iy);
    }
}

// K2: bilinear, direct from global — no LDS, no barriers (round-13 structure,
// best measured). XCD-aware swizzle: all 16 bands of an image run on the SAME
// XCD (bid%8 selects XCD on the 8-XCD MI355X), so the band-overlap rows and
// column-window re-reads are served by one 4 MB L2. Bijection on 6144 = 8*768.
// Per-pixel fp32 math identical to rounds 11-14 (verified).
__global__ __launch_bounds__(256) void bilinear_direct_kernel(
    const float* __restrict__ x, const int* __restrict__ se, float* __restrict__ out)
{
    // Invert the swizzle: work w -> image g = w>>4, band = w&15, with
    // xcd = g&7, slot = (g>>3)*16 + band, bid = slot*8 + xcd.
    const int bid  = blockIdx.x;
    const int xcd  = bid & 7;
    const int slot = bid >> 3;
    const int band = slot & 15;
    const int ghi  = slot >> 4;          // g >> 3
    const int bc   = ghi * 8 + xcd;      // image index (b*3 + c), 0..383
    const int ib   = band * TILE_I;      // first output row of this band

    const int b  = bc / 3;
    const int tid = threadIdx.x;

    const int x0 = se[2 * b];
    const int y0 = se[2 * b + 1];

    const float scale = (float)(229.0 / 255.0);   // (CROP-1)/(IMG-1) in fp32

    // Thread = output columns [4*jq, 4*jq+4), rows il = ilh + 4*k.
    const int jq  = tid & 63;
    const int ilh = tid >> 6;
    const int jb0 = 4 * jq;

    const float sj0 = (float)(jb0    ) * scale; const int a0 = (int)floorf(sj0); const float wj0 = sj0 - (float)a0;
    const float sj1 = (float)(jb0 + 1) * scale; const int a1 = (int)floorf(sj1); const float wj1 = sj1 - (float)a1;
    const float sj2 = (float)(jb0 + 2) * scale; const int a2 = (int)floorf(sj2); const float wj2 = sj2 - (float)a2;
    const float sj3 = (float)(jb0 + 3) * scale; const int a3 = (int)floorf(sj3); const float wj3 = sj3 - (float)a3;

    // Relative source-column indices (proven ranges): d1∈{0,1} d2∈{1,2} d3∈{2,3};
    // e3∈{2,3,4} (col 255 can clamp at 229).
    const int  d1 = a1 - a0;
    const int  d2 = a2 - a0;
    const int  d3 = a3 - a0;
    const int  e3 = min(a3 + 1, CROPW - 1) - a0;
    const int  cA = y0 + a0;
    const int  c4 = min(cA + 4, 255);       // clamp only when rb4 unused

    const float owj0 = 1.0f - wj0, owj1 = 1.0f - wj1;
    const float owj2 = 1.0f - wj2, owj3 = 1.0f - wj3;

    const float* img = x + (size_t)bc * (IMG * IMG);
    float* outbase = out + (size_t)bc * (IMG * IMG) + (size_t)ib * IMG + jb0;

    #pragma unroll
    for (int k = 0; k < 4; ++k) {
        const int   il = ilh + 4 * k;
        const int   i  = ib + il;
        const float si = (float)i * scale;
        const int   i0 = (int)floorf(si);
        const float wi = si - (float)i0;
        const int   i1 = min(i0 + 1, CROPW - 1);
        const int   r0g = (x0 + i0) << 8;
        const int   r1g = (x0 + i1) << 8;
        const float owi = 1.0f - wi;

        // Unaligned (4B-aligned) vector loads: HW dwordx4 needs only dword align.
        f32x4_t v, u;
        __builtin_memcpy(&v, img + r0g + cA, sizeof(f32x4_t));
        __builtin_memcpy(&u, img + r1g + cA, sizeof(f32x4_t));
        const float v4s = img[r0g + c4];
        const float u4s = img[r1g + c4];

        // Vertical blend once per source column (== reference "rows" values).
        const float rb0 = v.x * owi + u.x * wi;
        const float rb1 = v.y * owi + u.y * wi;
        const float rb2 = v.z * owi + u.z * wi;
        const float rb3 = v.w * owi + u.w * wi;
        const float rb4 = v4s * owi + u4s * wi;

        // Horizontal blend per pixel (static-range selects).
        const float o0 = rb0 * owj0 + rb1 * wj0;

        const float A1 = d1 ? rb1 : rb0;
        const float B1 = d1 ? rb2 : rb1;
        const float o1 = A1 * owj1 + B1 * wj1;

        const float A2 = (d2 == 2) ? rb2 : rb1;
        const float B2 = (d2 == 2) ? rb3 : rb2;
        const float o2 = A2 * owj2 + B2 * wj2;

        const float A3 = (d3 == 3) ? rb3 : rb2;
        const float B3 = (e3 == 2) ? rb2 : ((e3 == 3) ? rb3 : rb4);
        const float o3 = A3 * owj3 + B3 * wj3;

        f32x4_t o; o.x = o0; o.y = o1; o.z = o2; o.w = o3;
        __builtin_nontemporal_store(o, (f32x4_t*)(outbase + (size_t)il * IMG));
    }
}

extern "C" void kernel_launch(void* const* d_in, const int* in_sizes, int n_in,
                              void* d_out, int out_size, void* d_ws, size_t ws_size,
                              hipStream_t stream) {
    const float* x  = (const float*)d_in[0];   // (128,3,256,256)
    const float* fm = (const float*)d_in[1];   // (128,512,16,16)
    float* out = (float*)d_out;                // (128,3,256,256)

    int*   se       = (int*)d_ws;                               // 128*2 ints
    float* cam_part = (float*)((char*)d_ws + 1024);             // 2 MB

    cam_partial_kernel<<<128 * NGROUP, 256, 0, stream>>>(fm, cam_part);
    argmax_kernel<<<128, 256, 0, stream>>>(cam_part, se);

    bilinear_direct_kernel<<<384 * NTILE, 256, 0, stream>>>(x, se, out);
}